// Round 3
// baseline (652.376 us; speedup 1.0000x reference)
//
#include <hip/hip_runtime.h>

#define N_NODES 50000
#define N_EDGES 800000
#define E_TOT   850000           // edges + self loops
#define IN_DIM  128
#define HID     64
#define HEADS   4
#define C1      256              // HEADS*HID
#define OUT_DIM 64
#define NEG_SLOPE 0.2f

// ---------------------------------------------------------------------------
// CSR build (by destination): count -> exclusive scan -> fill
// ---------------------------------------------------------------------------
__global__ void count_kernel(const int* __restrict__ dst_a, int* __restrict__ deg)
{
    int j = blockIdx.x * blockDim.x + threadIdx.x;
    if (j >= E_TOT) return;
    int d = (j < N_EDGES) ? dst_a[j] : (j - N_EDGES);   // self loop
    atomicAdd(&deg[d], 1);
}

__global__ __launch_bounds__(1024) void scan_kernel(const int* __restrict__ deg,
                                                    int* __restrict__ rowptr)
{
    __shared__ int psum[1024];
    const int t = threadIdx.x;
    const int CH = (N_NODES + 1023) / 1024;            // 49
    const int base = t * CH;
    int s = 0;
    for (int i = 0; i < CH; i++) {
        int idx = base + i;
        if (idx < N_NODES) s += deg[idx];
    }
    psum[t] = s;
    __syncthreads();
    for (int off = 1; off < 1024; off <<= 1) {         // Hillis-Steele inclusive
        int v = (t >= off) ? psum[t - off] : 0;
        __syncthreads();
        psum[t] += v;
        __syncthreads();
    }
    int run = (t > 0) ? psum[t - 1] : 0;               // exclusive prefix of my chunk
    for (int i = 0; i < CH; i++) {
        int idx = base + i;
        if (idx < N_NODES) { rowptr[idx] = run; run += deg[idx]; }
    }
    if (t == 0) rowptr[N_NODES] = E_TOT;
}

__global__ void fill_kernel(const int* __restrict__ src_a, const int* __restrict__ dst_a,
                            const int* __restrict__ rowptr, int* __restrict__ cursor,
                            int* __restrict__ srcSorted)
{
    int j = blockIdx.x * blockDim.x + threadIdx.x;
    if (j >= E_TOT) return;
    int s, d;
    if (j < N_EDGES) { s = src_a[j]; d = dst_a[j]; }
    else             { s = j - N_EDGES; d = s; }
    int pos = atomicAdd(&cursor[d], 1);
    srcSorted[rowptr[d] + pos] = s;
}

// ---------------------------------------------------------------------------
// GEMM1: h1 = x @ W1  [50000x128]@[128x256], fused per-head projections.
// No LDS: x-tile elements are wave-uniform -> scalar (s_load) broadcast path.
// Thread t = output column; 16 nodes per block.
// ---------------------------------------------------------------------------
__global__ __launch_bounds__(256) void gemm1_kernel(
    const float* __restrict__ x, const float* __restrict__ W1,
    const float* __restrict__ a_src1, const float* __restrict__ a_dst1,
    float* __restrict__ h1, float* __restrict__ as1, float* __restrict__ ad1)
{
    const int t = threadIdx.x;
    const int nodeBase = blockIdx.x * 16;      // N_NODES % 16 == 0
    const float* xrow = x + (size_t)nodeBase * IN_DIM;

    float acc[16];
    #pragma unroll
    for (int n = 0; n < 16; n++) acc[n] = 0.f;

    for (int k = 0; k < IN_DIM; k += 4) {
        float w0 = W1[(k + 0) * C1 + t];
        float w1 = W1[(k + 1) * C1 + t];
        float w2 = W1[(k + 2) * C1 + t];
        float w3 = W1[(k + 3) * C1 + t];
        #pragma unroll
        for (int n = 0; n < 16; n++) {
            float4 xv = *(const float4*)(xrow + n * IN_DIM + k);   // wave-uniform
            acc[n] = fmaf(xv.x, w0, acc[n]);
            acc[n] = fmaf(xv.y, w1, acc[n]);
            acc[n] = fmaf(xv.z, w2, acc[n]);
            acc[n] = fmaf(xv.w, w3, acc[n]);
        }
    }

    #pragma unroll
    for (int n = 0; n < 16; n++)
        h1[(size_t)(nodeBase + n) * C1 + t] = acc[n];

    const int lane = t & 63;
    const int head = t >> 6;
    const float asw = a_src1[t];
    const float adw = a_dst1[t];
    #pragma unroll
    for (int n = 0; n < 16; n++) {
        float s = acc[n] * asw;
        float d = acc[n] * adw;
        #pragma unroll
        for (int off = 32; off; off >>= 1) {
            s += __shfl_down(s, off, 64);
            d += __shfl_down(d, off, 64);
        }
        if (lane == 0) {
            as1[(nodeBase + n) * HEADS + head] = s;
            ad1[(nodeBase + n) * HEADS + head] = d;
        }
    }
}

// ---------------------------------------------------------------------------
// Layer-1 aggregation, gather-style, unroll x4 for memory-level parallelism.
// One wave per dst node, lane = 4 channels. Epilogue fuses +b1 and ELU so
// gemm2 can read a pre-activated tile. No atomics.
// ---------------------------------------------------------------------------
__global__ __launch_bounds__(256) void agg1_kernel(
    const int* __restrict__ rowptr, const int* __restrict__ srcS,
    const float* __restrict__ h1, const float* __restrict__ as1,
    const float* __restrict__ ad1, const float* __restrict__ b1,
    float* __restrict__ act1)
{
    int gid  = blockIdx.x * blockDim.x + threadIdx.x;
    int n    = gid >> 6;
    int lane = threadIdx.x & 63;
    if (n >= N_NODES) return;
    const int h = lane >> 4;                       // head of my 4 channels
    const float adh = ad1[n * HEADS + h];
    const int e0 = rowptr[n], e1 = rowptr[n + 1];

    float4 acc = {0.f, 0.f, 0.f, 0.f};
    float den = 0.f;
    int e = e0;
    for (; e + 4 <= e1; e += 4) {                  // 4 independent load chains
        int s0 = srcS[e], s1 = srcS[e + 1], s2 = srcS[e + 2], s3 = srcS[e + 3];
        float a0 = as1[s0 * HEADS + h] + adh;
        float a1 = as1[s1 * HEADS + h] + adh;
        float a2 = as1[s2 * HEADS + h] + adh;
        float a3 = as1[s3 * HEADS + h] + adh;
        float4 v0 = *(const float4*)(h1 + (size_t)s0 * C1 + lane * 4);
        float4 v1 = *(const float4*)(h1 + (size_t)s1 * C1 + lane * 4);
        float4 v2 = *(const float4*)(h1 + (size_t)s2 * C1 + lane * 4);
        float4 v3 = *(const float4*)(h1 + (size_t)s3 * C1 + lane * 4);
        a0 = a0 > 0.f ? a0 : NEG_SLOPE * a0;
        a1 = a1 > 0.f ? a1 : NEG_SLOPE * a1;
        a2 = a2 > 0.f ? a2 : NEG_SLOPE * a2;
        a3 = a3 > 0.f ? a3 : NEG_SLOPE * a3;
        float w0 = __expf(a0), w1 = __expf(a1), w2 = __expf(a2), w3 = __expf(a3);
        acc.x = fmaf(w0, v0.x, acc.x); acc.y = fmaf(w0, v0.y, acc.y);
        acc.z = fmaf(w0, v0.z, acc.z); acc.w = fmaf(w0, v0.w, acc.w);
        acc.x = fmaf(w1, v1.x, acc.x); acc.y = fmaf(w1, v1.y, acc.y);
        acc.z = fmaf(w1, v1.z, acc.z); acc.w = fmaf(w1, v1.w, acc.w);
        acc.x = fmaf(w2, v2.x, acc.x); acc.y = fmaf(w2, v2.y, acc.y);
        acc.z = fmaf(w2, v2.z, acc.z); acc.w = fmaf(w2, v2.w, acc.w);
        acc.x = fmaf(w3, v3.x, acc.x); acc.y = fmaf(w3, v3.y, acc.y);
        acc.z = fmaf(w3, v3.z, acc.z); acc.w = fmaf(w3, v3.w, acc.w);
        den += (w0 + w1) + (w2 + w3);
    }
    for (; e < e1; e++) {                          // tail
        int s = srcS[e];
        float a = as1[s * HEADS + h] + adh;
        a = a > 0.f ? a : NEG_SLOPE * a;
        float w = __expf(a);
        float4 hv = *(const float4*)(h1 + (size_t)s * C1 + lane * 4);
        acc.x = fmaf(w, hv.x, acc.x); acc.y = fmaf(w, hv.y, acc.y);
        acc.z = fmaf(w, hv.z, acc.z); acc.w = fmaf(w, hv.w, acc.w);
        den += w;
    }
    float inv = 1.f / (den + 1e-16f);
    float4 bb = *(const float4*)(b1 + lane * 4);
    float o0 = fmaf(acc.x, inv, bb.x);
    float o1 = fmaf(acc.y, inv, bb.y);
    float o2 = fmaf(acc.z, inv, bb.z);
    float o3 = fmaf(acc.w, inv, bb.w);
    o0 = o0 > 0.f ? o0 : __expf(o0) - 1.f;         // ELU fused here
    o1 = o1 > 0.f ? o1 : __expf(o1) - 1.f;
    o2 = o2 > 0.f ? o2 : __expf(o2) - 1.f;
    o3 = o3 > 0.f ? o3 : __expf(o3) - 1.f;
    float4 o = {o0, o1, o2, o3};
    *(float4*)(act1 + (size_t)n * C1 + lane * 4) = o;
}

// ---------------------------------------------------------------------------
// GEMM2: h2 = act1 @ W2  [50000x256]@[256x64], fused as2/ad2 projections.
// act1 pre-activated; tile elements wave-uniform -> scalar path, no LDS.
// 256 threads = 4 waves; wave `sub` owns 4 nodes, thread col c = t&63.
// ---------------------------------------------------------------------------
__global__ __launch_bounds__(256) void gemm2_kernel(
    const float* __restrict__ act1, const float* __restrict__ W2,
    const float* __restrict__ a_src2, const float* __restrict__ a_dst2,
    float* __restrict__ h2, float* __restrict__ as2, float* __restrict__ ad2)
{
    const int t = threadIdx.x;
    const int nodeBase = blockIdx.x * 16;
    const int c = t & 63;
    const int sub = t >> 6;
    const float* arow = act1 + (size_t)(nodeBase + sub * 4) * C1;

    float acc[4];
    #pragma unroll
    for (int i = 0; i < 4; i++) acc[i] = 0.f;

    for (int k = 0; k < C1; k += 4) {
        float w0 = W2[(k + 0) * OUT_DIM + c];
        float w1 = W2[(k + 1) * OUT_DIM + c];
        float w2v = W2[(k + 2) * OUT_DIM + c];
        float w3 = W2[(k + 3) * OUT_DIM + c];
        #pragma unroll
        for (int i = 0; i < 4; i++) {
            float4 xv = *(const float4*)(arow + i * C1 + k);       // wave-uniform
            acc[i] = fmaf(xv.x, w0, acc[i]);
            acc[i] = fmaf(xv.y, w1, acc[i]);
            acc[i] = fmaf(xv.z, w2v, acc[i]);
            acc[i] = fmaf(xv.w, w3, acc[i]);
        }
    }

    const float asw = a_src2[c];
    const float adw = a_dst2[c];
    #pragma unroll
    for (int i = 0; i < 4; i++) {
        int node = nodeBase + sub * 4 + i;
        h2[(size_t)node * OUT_DIM + c] = acc[i];
        float s = acc[i] * asw;
        float dd = acc[i] * adw;
        #pragma unroll
        for (int off = 32; off; off >>= 1) {
            s  += __shfl_down(s, off, 64);
            dd += __shfl_down(dd, off, 64);
        }
        if (c == 0) { as2[node] = s; ad2[node] = dd; }
    }
}

// ---------------------------------------------------------------------------
// Layer-2 aggregation + bias + fc dot, fused, unroll x4. One wave per node,
// lane = channel (OUT_DIM=64). Writes final scalar out[n]. No atomics.
// ---------------------------------------------------------------------------
__global__ __launch_bounds__(256) void agg2_final_kernel(
    const int* __restrict__ rowptr, const int* __restrict__ srcS,
    const float* __restrict__ h2, const float* __restrict__ as2,
    const float* __restrict__ ad2, const float* __restrict__ b2,
    const float* __restrict__ fc_w, const float* __restrict__ fc_b,
    float* __restrict__ out)
{
    int gid  = blockIdx.x * blockDim.x + threadIdx.x;
    int n    = gid >> 6;
    int lane = threadIdx.x & 63;
    if (n >= N_NODES) return;
    const float adh = ad2[n];
    const int e0 = rowptr[n], e1 = rowptr[n + 1];

    float acc = 0.f, den = 0.f;
    int e = e0;
    for (; e + 4 <= e1; e += 4) {
        int s0 = srcS[e], s1 = srcS[e + 1], s2 = srcS[e + 2], s3 = srcS[e + 3];
        float a0 = as2[s0] + adh;
        float a1 = as2[s1] + adh;
        float a2 = as2[s2] + adh;
        float a3 = as2[s3] + adh;
        float v0 = h2[(size_t)s0 * OUT_DIM + lane];
        float v1 = h2[(size_t)s1 * OUT_DIM + lane];
        float v2 = h2[(size_t)s2 * OUT_DIM + lane];
        float v3 = h2[(size_t)s3 * OUT_DIM + lane];
        a0 = a0 > 0.f ? a0 : NEG_SLOPE * a0;
        a1 = a1 > 0.f ? a1 : NEG_SLOPE * a1;
        a2 = a2 > 0.f ? a2 : NEG_SLOPE * a2;
        a3 = a3 > 0.f ? a3 : NEG_SLOPE * a3;
        float w0 = __expf(a0), w1 = __expf(a1), w2 = __expf(a2), w3 = __expf(a3);
        acc = fmaf(w0, v0, acc); acc = fmaf(w1, v1, acc);
        acc = fmaf(w2, v2, acc); acc = fmaf(w3, v3, acc);
        den += (w0 + w1) + (w2 + w3);
    }
    for (; e < e1; e++) {
        int s = srcS[e];
        float a = as2[s] + adh;
        a = a > 0.f ? a : NEG_SLOPE * a;
        float w = __expf(a);
        acc = fmaf(w, h2[(size_t)s * OUT_DIM + lane], acc);
        den += w;
    }
    float v = acc / (den + 1e-16f) + b2[lane];
    float r = v * fc_w[lane];
    #pragma unroll
    for (int off = 32; off; off >>= 1) r += __shfl_down(r, off, 64);
    if (lane == 0) out[n] = r + fc_b[0];
}

extern "C" void kernel_launch(void* const* d_in, const int* in_sizes, int n_in,
                              void* d_out, int out_size, void* d_ws, size_t ws_size,
                              hipStream_t stream)
{
    const float* x      = (const float*)d_in[0];
    const int*   ei     = (const int*)d_in[1];
    const float* W1     = (const float*)d_in[2];
    const float* a_src1 = (const float*)d_in[3];
    const float* a_dst1 = (const float*)d_in[4];
    const float* b1     = (const float*)d_in[5];
    const float* W2     = (const float*)d_in[6];
    const float* a_src2 = (const float*)d_in[7];
    const float* a_dst2 = (const float*)d_in[8];
    const float* b2     = (const float*)d_in[9];
    const float* fc_w   = (const float*)d_in[10];
    const float* fc_b   = (const float*)d_in[11];
    float* out = (float*)d_out;

    const int* srcA = ei;
    const int* dstA = ei + N_EDGES;

    // workspace layout
    float* ws = (float*)d_ws;
    size_t off = 0;
    float* h1      = ws + off; off += (size_t)N_NODES * C1;       // 12.8M
    float* act1    = ws + off; off += (size_t)N_NODES * C1;       // 12.8M
    float* h2      = ws + off; off += (size_t)N_NODES * OUT_DIM;  //  3.2M
    float* as1     = ws + off; off += (size_t)N_NODES * HEADS;
    float* ad1     = ws + off; off += (size_t)N_NODES * HEADS;
    float* as2     = ws + off; off += N_NODES;
    float* ad2     = ws + off; off += N_NODES;
    int* rowptr    = (int*)(ws + off); off += N_NODES + 1 + 1;    // 50001 (+pad)
    int* srcSorted = (int*)(ws + off); off += E_TOT;
    int* zstart    = (int*)(ws + off);
    int* deg       = (int*)(ws + off); off += N_NODES;
    int* cursor    = (int*)(ws + off); off += N_NODES;
    hipMemsetAsync(zstart, 0, 2 * N_NODES * sizeof(int), stream);

    // CSR build
    count_kernel<<<(E_TOT + 255) / 256, 256, 0, stream>>>(dstA, deg);
    scan_kernel<<<1, 1024, 0, stream>>>(deg, rowptr);
    fill_kernel<<<(E_TOT + 255) / 256, 256, 0, stream>>>(srcA, dstA, rowptr, cursor, srcSorted);

    // layer 1
    gemm1_kernel<<<N_NODES / 16, 256, 0, stream>>>(x, W1, a_src1, a_dst1, h1, as1, ad1);
    agg1_kernel<<<(N_NODES * 64 + 255) / 256, 256, 0, stream>>>(rowptr, srcSorted, h1, as1, ad1, b1, act1);

    // layer 2 + final (bias/ELU already folded into act1)
    gemm2_kernel<<<N_NODES / 16, 256, 0, stream>>>(act1, W2, a_src2, a_dst2, h2, as2, ad2);
    agg2_final_kernel<<<(N_NODES * 64 + 255) / 256, 256, 0, stream>>>(rowptr, srcSorted, h2, as2, ad2, b2, fc_w, fc_b, out);
}

// Round 4
// 578.619 us; speedup vs baseline: 1.1275x; 1.1275x over previous
//
#include <hip/hip_runtime.h>

#define N_NODES 50000
#define N_EDGES 800000
#define E_TOT   850000           // edges + self loops
#define IN_DIM  128
#define HID     64
#define HEADS   4
#define C1      256              // HEADS*HID
#define OUT_DIM 64
#define NEG_SLOPE 0.2f

#define XS_STRIDE_H (IN_DIM + 4)             // 132: +4 breaks 4-way head conflicts
#define XS_STRIDE_N (HEADS * XS_STRIDE_H)    // 528
#define ACT_STRIDE  (C1 + 4)                 // 260: +4 breaks 4-way node conflicts

// ---------------------------------------------------------------------------
// CSR build (by destination): count -> exclusive scan -> fill
// ---------------------------------------------------------------------------
__global__ void count_kernel(const int* __restrict__ dst_a, int* __restrict__ deg)
{
    int j = blockIdx.x * blockDim.x + threadIdx.x;
    if (j >= E_TOT) return;
    int d = (j < N_EDGES) ? dst_a[j] : (j - N_EDGES);   // self loop
    atomicAdd(&deg[d], 1);
}

__global__ __launch_bounds__(1024) void scan_kernel(const int* __restrict__ deg,
                                                    int* __restrict__ rowptr)
{
    __shared__ int psum[1024];
    const int t = threadIdx.x;
    const int CH = (N_NODES + 1023) / 1024;            // 49
    const int base = t * CH;
    int s = 0;
    for (int i = 0; i < CH; i++) {
        int idx = base + i;
        if (idx < N_NODES) s += deg[idx];
    }
    psum[t] = s;
    __syncthreads();
    for (int off = 1; off < 1024; off <<= 1) {         // Hillis-Steele inclusive
        int v = (t >= off) ? psum[t - off] : 0;
        __syncthreads();
        psum[t] += v;
        __syncthreads();
    }
    int run = (t > 0) ? psum[t - 1] : 0;
    for (int i = 0; i < CH; i++) {
        int idx = base + i;
        if (idx < N_NODES) { rowptr[idx] = run; run += deg[idx]; }
    }
    if (t == 0) rowptr[N_NODES] = E_TOT;
}

__global__ void fill_kernel(const int* __restrict__ src_a, const int* __restrict__ dst_a,
                            const int* __restrict__ rowptr, int* __restrict__ cursor,
                            int* __restrict__ srcSorted)
{
    int j = blockIdx.x * blockDim.x + threadIdx.x;
    if (j >= E_TOT) return;
    int s, d;
    if (j < N_EDGES) { s = src_a[j]; d = dst_a[j]; }
    else             { s = j - N_EDGES; d = s; }
    int pos = atomicAdd(&cursor[d], 1);
    srcSorted[rowptr[d] + pos] = s;
}

// ---------------------------------------------------------------------------
// prep: p_src[k][h] = sum_c W1[k][h*64+c] * a_src1[h][c]  (and p_dst).
// Collapses the layer-1 logit projection to a single [128x4] matrix so
// as1 = x @ p_src (h1 never needed for logits). One block.
// ---------------------------------------------------------------------------
__global__ __launch_bounds__(512) void prep_kernel(
    const float* __restrict__ W1, const float* __restrict__ a_src1,
    const float* __restrict__ a_dst1,
    float* __restrict__ p_src, float* __restrict__ p_dst)
{
    const int t = threadIdx.x;                 // 512 = 128 k * 4 h
    const int k = t >> 2, h = t & 3;
    const float* wrow = W1 + k * C1 + h * HID;
    const float* as = a_src1 + h * HID;
    const float* ad = a_dst1 + h * HID;
    float s = 0.f, d = 0.f;
    for (int c = 0; c < HID; c++) {
        float w = wrow[c];
        s = fmaf(w, as[c], s);
        d = fmaf(w, ad[c], d);
    }
    p_src[k * HEADS + h] = s;
    p_dst[k * HEADS + h] = d;
}

// ---------------------------------------------------------------------------
// proj1: as1/ad1[n][4] = x[n] @ p_src / p_dst. One wave per node.
// ---------------------------------------------------------------------------
__global__ __launch_bounds__(256) void proj1_kernel(
    const float* __restrict__ x, const float* __restrict__ p_src,
    const float* __restrict__ p_dst, float* __restrict__ as1, float* __restrict__ ad1)
{
    __shared__ float ps[IN_DIM * HEADS];       // 2 KB
    __shared__ float pd[IN_DIM * HEADS];       // 2 KB
    const int t = threadIdx.x;
    for (int i = t; i < IN_DIM * HEADS; i += 256) { ps[i] = p_src[i]; pd[i] = p_dst[i]; }
    __syncthreads();
    const int node = blockIdx.x * 4 + (t >> 6);
    const int lane = t & 63;
    float2 xv = *(const float2*)(x + (size_t)node * IN_DIM + lane * 2);
    float4 p0 = *(const float4*)(ps + (lane * 2) * HEADS);
    float4 p1 = *(const float4*)(ps + (lane * 2 + 1) * HEADS);
    float4 q0 = *(const float4*)(pd + (lane * 2) * HEADS);
    float4 q1 = *(const float4*)(pd + (lane * 2 + 1) * HEADS);
    float s0 = xv.x * p0.x + xv.y * p1.x;
    float s1 = xv.x * p0.y + xv.y * p1.y;
    float s2 = xv.x * p0.z + xv.y * p1.z;
    float s3 = xv.x * p0.w + xv.y * p1.w;
    float d0 = xv.x * q0.x + xv.y * q1.x;
    float d1 = xv.x * q0.y + xv.y * q1.y;
    float d2 = xv.x * q0.z + xv.y * q1.z;
    float d3 = xv.x * q0.w + xv.y * q1.w;
    #pragma unroll
    for (int off = 32; off; off >>= 1) {
        s0 += __shfl_down(s0, off, 64); s1 += __shfl_down(s1, off, 64);
        s2 += __shfl_down(s2, off, 64); s3 += __shfl_down(s3, off, 64);
        d0 += __shfl_down(d0, off, 64); d1 += __shfl_down(d1, off, 64);
        d2 += __shfl_down(d2, off, 64); d3 += __shfl_down(d3, off, 64);
    }
    if (lane == 0) {
        float4 sv = {s0, s1, s2, s3};
        float4 dv = {d0, d1, d2, d3};
        *(float4*)(as1 + node * 4) = sv;
        *(float4*)(ad1 + node * 4) = dv;
    }
}

// ---------------------------------------------------------------------------
// agg1x: xagg[n][h][k] = sum_e alpha^h_e x[src_e][k]  (softmax-normalized).
// Gathers 512 B x-rows instead of 1 KB h1-rows (linearity of GAT aggregation).
// One wave per dst node, lane = 2 k-channels, 4 head-accumulators.
// ---------------------------------------------------------------------------
__global__ __launch_bounds__(256) void agg1x_kernel(
    const int* __restrict__ rowptr, const int* __restrict__ srcS,
    const float* __restrict__ x, const float* __restrict__ as1,
    const float* __restrict__ ad1, float* __restrict__ xagg)
{
    int gid  = blockIdx.x * blockDim.x + threadIdx.x;
    int n    = gid >> 6;
    int lane = threadIdx.x & 63;
    if (n >= N_NODES) return;
    float4 adv = *(const float4*)(ad1 + n * 4);
    const int e0 = rowptr[n], e1 = rowptr[n + 1];

    float2 acc0 = {0,0}, acc1 = {0,0}, acc2 = {0,0}, acc3 = {0,0};
    float den0 = 0, den1 = 0, den2 = 0, den3 = 0;
    int e = e0;
    for (; e + 2 <= e1; e += 2) {              // 2 row-loads in flight
        int s0 = srcS[e], s1 = srcS[e + 1];
        float4 A0 = *(const float4*)(as1 + s0 * 4);
        float4 A1 = *(const float4*)(as1 + s1 * 4);
        float2 xv0 = *(const float2*)(x + (size_t)s0 * IN_DIM + lane * 2);
        float2 xv1 = *(const float2*)(x + (size_t)s1 * IN_DIM + lane * 2);
        float a0 = A0.x + adv.x, a1 = A0.y + adv.y, a2 = A0.z + adv.z, a3 = A0.w + adv.w;
        a0 = a0 > 0.f ? a0 : NEG_SLOPE * a0;  a1 = a1 > 0.f ? a1 : NEG_SLOPE * a1;
        a2 = a2 > 0.f ? a2 : NEG_SLOPE * a2;  a3 = a3 > 0.f ? a3 : NEG_SLOPE * a3;
        float w0 = __expf(a0), w1 = __expf(a1), w2 = __expf(a2), w3 = __expf(a3);
        float b0 = A1.x + adv.x, b1v = A1.y + adv.y, b2v = A1.z + adv.z, b3 = A1.w + adv.w;
        b0 = b0 > 0.f ? b0 : NEG_SLOPE * b0;  b1v = b1v > 0.f ? b1v : NEG_SLOPE * b1v;
        b2v = b2v > 0.f ? b2v : NEG_SLOPE * b2v;  b3 = b3 > 0.f ? b3 : NEG_SLOPE * b3;
        float u0 = __expf(b0), u1 = __expf(b1v), u2 = __expf(b2v), u3 = __expf(b3);
        acc0.x = fmaf(w0, xv0.x, acc0.x); acc0.y = fmaf(w0, xv0.y, acc0.y);
        acc1.x = fmaf(w1, xv0.x, acc1.x); acc1.y = fmaf(w1, xv0.y, acc1.y);
        acc2.x = fmaf(w2, xv0.x, acc2.x); acc2.y = fmaf(w2, xv0.y, acc2.y);
        acc3.x = fmaf(w3, xv0.x, acc3.x); acc3.y = fmaf(w3, xv0.y, acc3.y);
        acc0.x = fmaf(u0, xv1.x, acc0.x); acc0.y = fmaf(u0, xv1.y, acc0.y);
        acc1.x = fmaf(u1, xv1.x, acc1.x); acc1.y = fmaf(u1, xv1.y, acc1.y);
        acc2.x = fmaf(u2, xv1.x, acc2.x); acc2.y = fmaf(u2, xv1.y, acc2.y);
        acc3.x = fmaf(u3, xv1.x, acc3.x); acc3.y = fmaf(u3, xv1.y, acc3.y);
        den0 += w0 + u0; den1 += w1 + u1; den2 += w2 + u2; den3 += w3 + u3;
    }
    for (; e < e1; e++) {
        int s = srcS[e];
        float4 A0 = *(const float4*)(as1 + s * 4);
        float2 xv = *(const float2*)(x + (size_t)s * IN_DIM + lane * 2);
        float a0 = A0.x + adv.x, a1 = A0.y + adv.y, a2 = A0.z + adv.z, a3 = A0.w + adv.w;
        a0 = a0 > 0.f ? a0 : NEG_SLOPE * a0;  a1 = a1 > 0.f ? a1 : NEG_SLOPE * a1;
        a2 = a2 > 0.f ? a2 : NEG_SLOPE * a2;  a3 = a3 > 0.f ? a3 : NEG_SLOPE * a3;
        float w0 = __expf(a0), w1 = __expf(a1), w2 = __expf(a2), w3 = __expf(a3);
        acc0.x = fmaf(w0, xv.x, acc0.x); acc0.y = fmaf(w0, xv.y, acc0.y);
        acc1.x = fmaf(w1, xv.x, acc1.x); acc1.y = fmaf(w1, xv.y, acc1.y);
        acc2.x = fmaf(w2, xv.x, acc2.x); acc2.y = fmaf(w2, xv.y, acc2.y);
        acc3.x = fmaf(w3, xv.x, acc3.x); acc3.y = fmaf(w3, xv.y, acc3.y);
        den0 += w0; den1 += w1; den2 += w2; den3 += w3;
    }
    float i0 = 1.f / (den0 + 1e-16f), i1 = 1.f / (den1 + 1e-16f);
    float i2 = 1.f / (den2 + 1e-16f), i3 = 1.f / (den3 + 1e-16f);
    float* o = xagg + (size_t)n * (HEADS * IN_DIM) + lane * 2;
    float2 r0 = {acc0.x * i0, acc0.y * i0};
    float2 r1 = {acc1.x * i1, acc1.y * i1};
    float2 r2 = {acc2.x * i2, acc2.y * i2};
    float2 r3 = {acc3.x * i3, acc3.y * i3};
    *(float2*)(o + 0 * IN_DIM) = r0;
    *(float2*)(o + 1 * IN_DIM) = r1;
    *(float2*)(o + 2 * IN_DIM) = r2;
    *(float2*)(o + 3 * IN_DIM) = r3;
}

// ---------------------------------------------------------------------------
// mlp: fused  out1 = xagg @ W1 (per head) + b1 -> ELU -> h2 = act @ W2,
// plus as2/ad2 projections. 16 nodes per block, act tile stays in LDS.
// Phase B: thread = (4 cols x 4 nodes) register tile -> 16 FMA per LDS read.
// ---------------------------------------------------------------------------
__global__ __launch_bounds__(256) void mlp_kernel(
    const float* __restrict__ xagg, const float* __restrict__ W1,
    const float* __restrict__ b1, const float* __restrict__ W2,
    const float* __restrict__ a_src2, const float* __restrict__ a_dst2,
    float* __restrict__ h2, float* __restrict__ as2, float* __restrict__ ad2)
{
    __shared__ float xs[16 * XS_STRIDE_N];     // 33 KB
    __shared__ float act[16 * ACT_STRIDE];     // 16.6 KB
    const int t = threadIdx.x;
    const int nodeBase = blockIdx.x * 16;

    {   // Phase A: stage xagg tile (coalesced 32 floats/thread)
        const int n = t >> 4, h = (t >> 2) & 3, k0 = (t & 3) * 32;
        const float* gsrc = xagg + (size_t)(nodeBase + n) * (HEADS * IN_DIM) + h * IN_DIM + k0;
        float* ld = xs + n * XS_STRIDE_N + h * XS_STRIDE_H + k0;
        #pragma unroll
        for (int j = 0; j < 32; j += 4)
            *(float4*)(ld + j) = *(const float4*)(gsrc + j);
    }
    __syncthreads();

    {   // Phase B: act = ELU(xagg @ W1 + b1)
        const int cg = t & 63;                 // cols 4cg..4cg+3 (head = cg>>4)
        const int g  = t >> 6;                 // nodes 4g..4g+3
        const int c0 = cg * 4;
        const int h  = cg >> 4;
        float acc[4][4];
        #pragma unroll
        for (int i = 0; i < 4; i++)
            #pragma unroll
            for (int m = 0; m < 4; m++) acc[i][m] = 0.f;
        const float* xbase = xs + (g * 4) * XS_STRIDE_N + h * XS_STRIDE_H;
        for (int k = 0; k < IN_DIM; k += 4) {
            float4 w0 = *(const float4*)(W1 + (size_t)(k + 0) * C1 + c0);
            float4 w1 = *(const float4*)(W1 + (size_t)(k + 1) * C1 + c0);
            float4 w2 = *(const float4*)(W1 + (size_t)(k + 2) * C1 + c0);
            float4 w3 = *(const float4*)(W1 + (size_t)(k + 3) * C1 + c0);
            #pragma unroll
            for (int i = 0; i < 4; i++) {
                float4 xv = *(const float4*)(xbase + i * XS_STRIDE_N + k);
                acc[i][0] = fmaf(xv.x, w0.x, acc[i][0]); acc[i][0] = fmaf(xv.y, w1.x, acc[i][0]);
                acc[i][0] = fmaf(xv.z, w2.x, acc[i][0]); acc[i][0] = fmaf(xv.w, w3.x, acc[i][0]);
                acc[i][1] = fmaf(xv.x, w0.y, acc[i][1]); acc[i][1] = fmaf(xv.y, w1.y, acc[i][1]);
                acc[i][1] = fmaf(xv.z, w2.y, acc[i][1]); acc[i][1] = fmaf(xv.w, w3.y, acc[i][1]);
                acc[i][2] = fmaf(xv.x, w0.z, acc[i][2]); acc[i][2] = fmaf(xv.y, w1.z, acc[i][2]);
                acc[i][2] = fmaf(xv.z, w2.z, acc[i][2]); acc[i][2] = fmaf(xv.w, w3.z, acc[i][2]);
                acc[i][3] = fmaf(xv.x, w0.w, acc[i][3]); acc[i][3] = fmaf(xv.y, w1.w, acc[i][3]);
                acc[i][3] = fmaf(xv.z, w2.w, acc[i][3]); acc[i][3] = fmaf(xv.w, w3.w, acc[i][3]);
            }
        }
        float4 bb = *(const float4*)(b1 + c0);
        #pragma unroll
        for (int i = 0; i < 4; i++) {
            float o0 = acc[i][0] + bb.x, o1 = acc[i][1] + bb.y;
            float o2 = acc[i][2] + bb.z, o3 = acc[i][3] + bb.w;
            o0 = o0 > 0.f ? o0 : __expf(o0) - 1.f;
            o1 = o1 > 0.f ? o1 : __expf(o1) - 1.f;
            o2 = o2 > 0.f ? o2 : __expf(o2) - 1.f;
            o3 = o3 > 0.f ? o3 : __expf(o3) - 1.f;
            float4 ov = {o0, o1, o2, o3};
            *(float4*)(act + (g * 4 + i) * ACT_STRIDE + c0) = ov;
        }
    }
    __syncthreads();

    {   // Phase C: h2 = act @ W2, fused as2/ad2
        const int n  = t >> 4;                 // node 0..15
        const int c0 = (t & 15) * 4;           // cols 0..63
        float a0 = 0.f, a1 = 0.f, a2 = 0.f, a3 = 0.f;
        const float* abase = act + n * ACT_STRIDE;
        for (int k = 0; k < C1; k += 4) {
            float4 xv = *(const float4*)(abase + k);
            float4 w0 = *(const float4*)(W2 + (size_t)(k + 0) * OUT_DIM + c0);
            float4 w1 = *(const float4*)(W2 + (size_t)(k + 1) * OUT_DIM + c0);
            float4 w2 = *(const float4*)(W2 + (size_t)(k + 2) * OUT_DIM + c0);
            float4 w3 = *(const float4*)(W2 + (size_t)(k + 3) * OUT_DIM + c0);
            a0 = fmaf(xv.x, w0.x, a0); a0 = fmaf(xv.y, w1.x, a0);
            a0 = fmaf(xv.z, w2.x, a0); a0 = fmaf(xv.w, w3.x, a0);
            a1 = fmaf(xv.x, w0.y, a1); a1 = fmaf(xv.y, w1.y, a1);
            a1 = fmaf(xv.z, w2.y, a1); a1 = fmaf(xv.w, w3.y, a1);
            a2 = fmaf(xv.x, w0.z, a2); a2 = fmaf(xv.y, w1.z, a2);
            a2 = fmaf(xv.z, w2.z, a2); a2 = fmaf(xv.w, w3.z, a2);
            a3 = fmaf(xv.x, w0.w, a3); a3 = fmaf(xv.y, w1.w, a3);
            a3 = fmaf(xv.z, w2.w, a3); a3 = fmaf(xv.w, w3.w, a3);
        }
        const int node = nodeBase + n;
        float4 hv = {a0, a1, a2, a3};
        *(float4*)(h2 + (size_t)node * OUT_DIM + c0) = hv;
        float4 aw = *(const float4*)(a_src2 + c0);
        float4 dw = *(const float4*)(a_dst2 + c0);
        float s = a0 * aw.x + a1 * aw.y + a2 * aw.z + a3 * aw.w;
        float d = a0 * dw.x + a1 * dw.y + a2 * dw.z + a3 * dw.w;
        #pragma unroll
        for (int off = 8; off; off >>= 1) {
            s += __shfl_down(s, off, 16);
            d += __shfl_down(d, off, 16);
        }
        if ((t & 15) == 0) { as2[node] = s; ad2[node] = d; }
    }
}

// ---------------------------------------------------------------------------
// Layer-2 aggregation + bias + fc dot, fused, unroll x4. One wave per node.
// ---------------------------------------------------------------------------
__global__ __launch_bounds__(256) void agg2_final_kernel(
    const int* __restrict__ rowptr, const int* __restrict__ srcS,
    const float* __restrict__ h2, const float* __restrict__ as2,
    const float* __restrict__ ad2, const float* __restrict__ b2,
    const float* __restrict__ fc_w, const float* __restrict__ fc_b,
    float* __restrict__ out)
{
    int gid  = blockIdx.x * blockDim.x + threadIdx.x;
    int n    = gid >> 6;
    int lane = threadIdx.x & 63;
    if (n >= N_NODES) return;
    const float adh = ad2[n];
    const int e0 = rowptr[n], e1 = rowptr[n + 1];

    float acc = 0.f, den = 0.f;
    int e = e0;
    for (; e + 4 <= e1; e += 4) {
        int s0 = srcS[e], s1 = srcS[e + 1], s2 = srcS[e + 2], s3 = srcS[e + 3];
        float a0 = as2[s0] + adh;
        float a1 = as2[s1] + adh;
        float a2 = as2[s2] + adh;
        float a3 = as2[s3] + adh;
        float v0 = h2[(size_t)s0 * OUT_DIM + lane];
        float v1 = h2[(size_t)s1 * OUT_DIM + lane];
        float v2 = h2[(size_t)s2 * OUT_DIM + lane];
        float v3 = h2[(size_t)s3 * OUT_DIM + lane];
        a0 = a0 > 0.f ? a0 : NEG_SLOPE * a0;
        a1 = a1 > 0.f ? a1 : NEG_SLOPE * a1;
        a2 = a2 > 0.f ? a2 : NEG_SLOPE * a2;
        a3 = a3 > 0.f ? a3 : NEG_SLOPE * a3;
        float w0 = __expf(a0), w1 = __expf(a1), w2 = __expf(a2), w3 = __expf(a3);
        acc = fmaf(w0, v0, acc); acc = fmaf(w1, v1, acc);
        acc = fmaf(w2, v2, acc); acc = fmaf(w3, v3, acc);
        den += (w0 + w1) + (w2 + w3);
    }
    for (; e < e1; e++) {
        int s = srcS[e];
        float a = as2[s] + adh;
        a = a > 0.f ? a : NEG_SLOPE * a;
        float w = __expf(a);
        acc = fmaf(w, h2[(size_t)s * OUT_DIM + lane], acc);
        den += w;
    }
    float v = acc / (den + 1e-16f) + b2[lane];
    float r = v * fc_w[lane];
    #pragma unroll
    for (int off = 32; off; off >>= 1) r += __shfl_down(r, off, 64);
    if (lane == 0) out[n] = r + fc_b[0];
}

extern "C" void kernel_launch(void* const* d_in, const int* in_sizes, int n_in,
                              void* d_out, int out_size, void* d_ws, size_t ws_size,
                              hipStream_t stream)
{
    const float* x      = (const float*)d_in[0];
    const int*   ei     = (const int*)d_in[1];
    const float* W1     = (const float*)d_in[2];
    const float* a_src1 = (const float*)d_in[3];
    const float* a_dst1 = (const float*)d_in[4];
    const float* b1     = (const float*)d_in[5];
    const float* W2     = (const float*)d_in[6];
    const float* a_src2 = (const float*)d_in[7];
    const float* a_dst2 = (const float*)d_in[8];
    const float* b2     = (const float*)d_in[9];
    const float* fc_w   = (const float*)d_in[10];
    const float* fc_b   = (const float*)d_in[11];
    float* out = (float*)d_out;

    const int* srcA = ei;
    const int* dstA = ei + N_EDGES;

    // workspace layout
    float* ws = (float*)d_ws;
    size_t off = 0;
    float* xagg    = ws + off; off += (size_t)N_NODES * HEADS * IN_DIM;  // 102.4 MB
    float* h2      = ws + off; off += (size_t)N_NODES * OUT_DIM;         //  12.8 MB
    float* as1     = ws + off; off += (size_t)N_NODES * HEADS;
    float* ad1     = ws + off; off += (size_t)N_NODES * HEADS;
    float* as2     = ws + off; off += N_NODES;
    float* ad2     = ws + off; off += N_NODES;
    float* p_src   = ws + off; off += IN_DIM * HEADS;
    float* p_dst   = ws + off; off += IN_DIM * HEADS;
    int* rowptr    = (int*)(ws + off); off += N_NODES + 2;
    int* srcSorted = (int*)(ws + off); off += E_TOT;
    int* zstart    = (int*)(ws + off);
    int* deg       = (int*)(ws + off); off += N_NODES;
    int* cursor    = (int*)(ws + off); off += N_NODES;
    hipMemsetAsync(zstart, 0, 2 * N_NODES * sizeof(int), stream);

    // CSR build
    count_kernel<<<(E_TOT + 255) / 256, 256, 0, stream>>>(dstA, deg);
    scan_kernel<<<1, 1024, 0, stream>>>(deg, rowptr);
    fill_kernel<<<(E_TOT + 255) / 256, 256, 0, stream>>>(srcA, dstA, rowptr, cursor, srcSorted);

    // layer-1 logit projections (h1 never materialized)
    prep_kernel<<<1, 512, 0, stream>>>(W1, a_src1, a_dst1, p_src, p_dst);
    proj1_kernel<<<N_NODES / 4, 256, 0, stream>>>(x, p_src, p_dst, as1, ad1);

    // layer-1 aggregation in x-space (512 B rows), then fused MLP
    agg1x_kernel<<<(N_NODES * 64 + 255) / 256, 256, 0, stream>>>(rowptr, srcSorted, x, as1, ad1, xagg);
    mlp_kernel<<<N_NODES / 16, 256, 0, stream>>>(xagg, W1, b1, W2, a_src2, a_dst2, h2, as2, ad2);

    // layer 2 + final
    agg2_final_kernel<<<(N_NODES * 64 + 255) / 256, 256, 0, stream>>>(rowptr, srcSorted, h2, as2, ad2, b2, fc_w, fc_b, out);
}

// Round 5
// 564.679 us; speedup vs baseline: 1.1553x; 1.0247x over previous
//
#include <hip/hip_runtime.h>

#define N_NODES 50000
#define N_EDGES 800000
#define E_TOT   850000           // edges + self loops
#define IN_DIM  128
#define HID     64
#define HEADS   4
#define C1      256              // HEADS*HID
#define OUT_DIM 64
#define NEG_SLOPE 0.2f

// LDS strides (floats). XS_STRIDE_N must be ==0 mod 4 (b128 alignment) and
// ==4 mod 8 so phase-B's 4 node-groups land on banks {0,16,0,16} (2-way, free).
#define XS_STRIDE_H 132
#define XS_STRIDE_N 532                      // 4*XS_STRIDE_H + 4
#define ACT_STRIDE  (C1 + 4)                 // 260
#define PC_STRIDE   68                       // phase-C partials: 64 + 4
#define PC_WCHUNK   (16 * PC_STRIDE)         // 1088

// ---------------------------------------------------------------------------
// CSR build (by destination): count -> exclusive scan -> fill
// ---------------------------------------------------------------------------
__global__ void count_kernel(const int* __restrict__ dst_a, int* __restrict__ deg)
{
    int j = blockIdx.x * blockDim.x + threadIdx.x;
    if (j >= E_TOT) return;
    int d = (j < N_EDGES) ? dst_a[j] : (j - N_EDGES);   // self loop
    atomicAdd(&deg[d], 1);
}

__global__ __launch_bounds__(1024) void scan_kernel(const int* __restrict__ deg,
                                                    int* __restrict__ rowptr)
{
    __shared__ int psum[1024];
    const int t = threadIdx.x;
    const int CH = (N_NODES + 1023) / 1024;            // 49
    const int base = t * CH;
    int s = 0;
    for (int i = 0; i < CH; i++) {
        int idx = base + i;
        if (idx < N_NODES) s += deg[idx];
    }
    psum[t] = s;
    __syncthreads();
    for (int off = 1; off < 1024; off <<= 1) {         // Hillis-Steele inclusive
        int v = (t >= off) ? psum[t - off] : 0;
        __syncthreads();
        psum[t] += v;
        __syncthreads();
    }
    int run = (t > 0) ? psum[t - 1] : 0;
    for (int i = 0; i < CH; i++) {
        int idx = base + i;
        if (idx < N_NODES) { rowptr[idx] = run; run += deg[idx]; }
    }
    if (t == 0) rowptr[N_NODES] = E_TOT;
}

__global__ void fill_kernel(const int* __restrict__ src_a, const int* __restrict__ dst_a,
                            const int* __restrict__ rowptr, int* __restrict__ cursor,
                            int* __restrict__ srcSorted)
{
    int j = blockIdx.x * blockDim.x + threadIdx.x;
    if (j >= E_TOT) return;
    int s, d;
    if (j < N_EDGES) { s = src_a[j]; d = dst_a[j]; }
    else             { s = j - N_EDGES; d = s; }
    int pos = atomicAdd(&cursor[d], 1);
    srcSorted[rowptr[d] + pos] = s;
}

// ---------------------------------------------------------------------------
// prep: p_src[k][h] = sum_c W1[k][h*64+c] * a_src1[h][c]  (and p_dst).
// ---------------------------------------------------------------------------
__global__ __launch_bounds__(512) void prep_kernel(
    const float* __restrict__ W1, const float* __restrict__ a_src1,
    const float* __restrict__ a_dst1,
    float* __restrict__ p_src, float* __restrict__ p_dst)
{
    const int t = threadIdx.x;                 // 512 = 128 k * 4 h
    const int k = t >> 2, h = t & 3;
    const float* wrow = W1 + k * C1 + h * HID;
    const float* as = a_src1 + h * HID;
    const float* ad = a_dst1 + h * HID;
    float s = 0.f, d = 0.f;
    for (int c = 0; c < HID; c++) {
        float w = wrow[c];
        s = fmaf(w, as[c], s);
        d = fmaf(w, ad[c], d);
    }
    p_src[k * HEADS + h] = s;
    p_dst[k * HEADS + h] = d;
}

// ---------------------------------------------------------------------------
// proj1: as1/ad1[n][4] = x[n] @ p_src / p_dst. One wave per node.
// ---------------------------------------------------------------------------
__global__ __launch_bounds__(256) void proj1_kernel(
    const float* __restrict__ x, const float* __restrict__ p_src,
    const float* __restrict__ p_dst, float* __restrict__ as1, float* __restrict__ ad1)
{
    __shared__ float ps[IN_DIM * HEADS];       // 2 KB
    __shared__ float pd[IN_DIM * HEADS];       // 2 KB
    const int t = threadIdx.x;
    for (int i = t; i < IN_DIM * HEADS; i += 256) { ps[i] = p_src[i]; pd[i] = p_dst[i]; }
    __syncthreads();
    const int node = blockIdx.x * 4 + (t >> 6);
    const int lane = t & 63;
    float2 xv = *(const float2*)(x + (size_t)node * IN_DIM + lane * 2);
    float4 p0 = *(const float4*)(ps + (lane * 2) * HEADS);
    float4 p1 = *(const float4*)(ps + (lane * 2 + 1) * HEADS);
    float4 q0 = *(const float4*)(pd + (lane * 2) * HEADS);
    float4 q1 = *(const float4*)(pd + (lane * 2 + 1) * HEADS);
    float s0 = xv.x * p0.x + xv.y * p1.x;
    float s1 = xv.x * p0.y + xv.y * p1.y;
    float s2 = xv.x * p0.z + xv.y * p1.z;
    float s3 = xv.x * p0.w + xv.y * p1.w;
    float d0 = xv.x * q0.x + xv.y * q1.x;
    float d1 = xv.x * q0.y + xv.y * q1.y;
    float d2 = xv.x * q0.z + xv.y * q1.z;
    float d3 = xv.x * q0.w + xv.y * q1.w;
    #pragma unroll
    for (int off = 32; off; off >>= 1) {
        s0 += __shfl_down(s0, off, 64); s1 += __shfl_down(s1, off, 64);
        s2 += __shfl_down(s2, off, 64); s3 += __shfl_down(s3, off, 64);
        d0 += __shfl_down(d0, off, 64); d1 += __shfl_down(d1, off, 64);
        d2 += __shfl_down(d2, off, 64); d3 += __shfl_down(d3, off, 64);
    }
    if (lane == 0) {
        float4 sv = {s0, s1, s2, s3};
        float4 dv = {d0, d1, d2, d3};
        *(float4*)(as1 + node * 4) = sv;
        *(float4*)(ad1 + node * 4) = dv;
    }
}

// ---------------------------------------------------------------------------
// gat1_mlp: fused per 16-node tile:
//   Gather: softmax-weighted sum of x[src] rows -> xs LDS tile (no xagg in HBM)
//   Phase B: act = ELU(xs @ W1 + b1); wave = head -> W1 read ONCE per block
//   Phase C: h2 = act @ W2, k-split across waves + LDS reduction -> W2 once
//   Epilogue: h2 store + as2/ad2 projections
// ---------------------------------------------------------------------------
__global__ __launch_bounds__(256) void gat1_mlp_kernel(
    const int* __restrict__ rowptr, const int* __restrict__ srcS,
    const float* __restrict__ x, const float* __restrict__ as1,
    const float* __restrict__ ad1,
    const float* __restrict__ W1, const float* __restrict__ b1,
    const float* __restrict__ W2,
    const float* __restrict__ a_src2, const float* __restrict__ a_dst2,
    float* __restrict__ h2, float* __restrict__ as2, float* __restrict__ ad2)
{
    __shared__ float xs[16 * XS_STRIDE_N];     // 34,048 B (aliased as pc later)
    __shared__ float act[16 * ACT_STRIDE];     // 16,640 B
    const int t = threadIdx.x;
    const int nodeBase = blockIdx.x * 16;
    const int lane = t & 63;
    const int wv = t >> 6;

    // ---- Gather phase: wave wv handles local nodes 4wv..4wv+3 ----
    for (int i = 0; i < 4; i++) {
        const int ln = wv * 4 + i;
        const int n = nodeBase + ln;
        float4 adv = *(const float4*)(ad1 + n * 4);
        const int e0 = rowptr[n], e1 = rowptr[n + 1];
        float2 acc0 = {0,0}, acc1 = {0,0}, acc2 = {0,0}, acc3 = {0,0};
        float den0 = 0, den1 = 0, den2 = 0, den3 = 0;
        int e = e0;
        for (; e + 2 <= e1; e += 2) {          // 2 row-loads in flight
            int s0 = srcS[e], s1 = srcS[e + 1];
            float4 A0 = *(const float4*)(as1 + s0 * 4);
            float4 A1 = *(const float4*)(as1 + s1 * 4);
            float2 xv0 = *(const float2*)(x + (size_t)s0 * IN_DIM + lane * 2);
            float2 xv1 = *(const float2*)(x + (size_t)s1 * IN_DIM + lane * 2);
            float a0 = A0.x + adv.x, a1 = A0.y + adv.y, a2 = A0.z + adv.z, a3 = A0.w + adv.w;
            a0 = a0 > 0.f ? a0 : NEG_SLOPE * a0;  a1 = a1 > 0.f ? a1 : NEG_SLOPE * a1;
            a2 = a2 > 0.f ? a2 : NEG_SLOPE * a2;  a3 = a3 > 0.f ? a3 : NEG_SLOPE * a3;
            float w0 = __expf(a0), w1 = __expf(a1), w2 = __expf(a2), w3 = __expf(a3);
            float b0 = A1.x + adv.x, b1v = A1.y + adv.y, b2v = A1.z + adv.z, b3 = A1.w + adv.w;
            b0 = b0 > 0.f ? b0 : NEG_SLOPE * b0;    b1v = b1v > 0.f ? b1v : NEG_SLOPE * b1v;
            b2v = b2v > 0.f ? b2v : NEG_SLOPE * b2v; b3 = b3 > 0.f ? b3 : NEG_SLOPE * b3;
            float u0 = __expf(b0), u1 = __expf(b1v), u2 = __expf(b2v), u3 = __expf(b3);
            acc0.x = fmaf(w0, xv0.x, acc0.x); acc0.y = fmaf(w0, xv0.y, acc0.y);
            acc1.x = fmaf(w1, xv0.x, acc1.x); acc1.y = fmaf(w1, xv0.y, acc1.y);
            acc2.x = fmaf(w2, xv0.x, acc2.x); acc2.y = fmaf(w2, xv0.y, acc2.y);
            acc3.x = fmaf(w3, xv0.x, acc3.x); acc3.y = fmaf(w3, xv0.y, acc3.y);
            acc0.x = fmaf(u0, xv1.x, acc0.x); acc0.y = fmaf(u0, xv1.y, acc0.y);
            acc1.x = fmaf(u1, xv1.x, acc1.x); acc1.y = fmaf(u1, xv1.y, acc1.y);
            acc2.x = fmaf(u2, xv1.x, acc2.x); acc2.y = fmaf(u2, xv1.y, acc2.y);
            acc3.x = fmaf(u3, xv1.x, acc3.x); acc3.y = fmaf(u3, xv1.y, acc3.y);
            den0 += w0 + u0; den1 += w1 + u1; den2 += w2 + u2; den3 += w3 + u3;
        }
        for (; e < e1; e++) {
            int s = srcS[e];
            float4 A0 = *(const float4*)(as1 + s * 4);
            float2 xv = *(const float2*)(x + (size_t)s * IN_DIM + lane * 2);
            float a0 = A0.x + adv.x, a1 = A0.y + adv.y, a2 = A0.z + adv.z, a3 = A0.w + adv.w;
            a0 = a0 > 0.f ? a0 : NEG_SLOPE * a0;  a1 = a1 > 0.f ? a1 : NEG_SLOPE * a1;
            a2 = a2 > 0.f ? a2 : NEG_SLOPE * a2;  a3 = a3 > 0.f ? a3 : NEG_SLOPE * a3;
            float w0 = __expf(a0), w1 = __expf(a1), w2 = __expf(a2), w3 = __expf(a3);
            acc0.x = fmaf(w0, xv.x, acc0.x); acc0.y = fmaf(w0, xv.y, acc0.y);
            acc1.x = fmaf(w1, xv.x, acc1.x); acc1.y = fmaf(w1, xv.y, acc1.y);
            acc2.x = fmaf(w2, xv.x, acc2.x); acc2.y = fmaf(w2, xv.y, acc2.y);
            acc3.x = fmaf(w3, xv.x, acc3.x); acc3.y = fmaf(w3, xv.y, acc3.y);
            den0 += w0; den1 += w1; den2 += w2; den3 += w3;
        }
        float i0 = 1.f / (den0 + 1e-16f), i1 = 1.f / (den1 + 1e-16f);
        float i2 = 1.f / (den2 + 1e-16f), i3 = 1.f / (den3 + 1e-16f);
        float* o = xs + ln * XS_STRIDE_N + lane * 2;
        float2 r0 = {acc0.x * i0, acc0.y * i0};
        float2 r1 = {acc1.x * i1, acc1.y * i1};
        float2 r2 = {acc2.x * i2, acc2.y * i2};
        float2 r3 = {acc3.x * i3, acc3.y * i3};
        *(float2*)(o + 0 * XS_STRIDE_H) = r0;
        *(float2*)(o + 1 * XS_STRIDE_H) = r1;
        *(float2*)(o + 2 * XS_STRIDE_H) = r2;
        *(float2*)(o + 3 * XS_STRIDE_H) = r3;
    }
    __syncthreads();

    {   // ---- Phase B: act = ELU(xs @ W1 + b1). wave = head. ----
        const int q  = t & 15;                 // col-quad within head
        const int g  = (t >> 4) & 3;           // node group (4 nodes)
        const int h  = wv;                     // head = wave
        const int c0 = h * HID + q * 4;        // column in [0,256)
        float acc[4][4];
        #pragma unroll
        for (int i = 0; i < 4; i++)
            #pragma unroll
            for (int m = 0; m < 4; m++) acc[i][m] = 0.f;
        const float* xbase = xs + (g * 4) * XS_STRIDE_N + h * XS_STRIDE_H;
        for (int k = 0; k < IN_DIM; k += 4) {
            float4 w0 = *(const float4*)(W1 + (size_t)(k + 0) * C1 + c0);
            float4 w1 = *(const float4*)(W1 + (size_t)(k + 1) * C1 + c0);
            float4 w2 = *(const float4*)(W1 + (size_t)(k + 2) * C1 + c0);
            float4 w3 = *(const float4*)(W1 + (size_t)(k + 3) * C1 + c0);
            #pragma unroll
            for (int i = 0; i < 4; i++) {
                float4 xv = *(const float4*)(xbase + i * XS_STRIDE_N + k);
                acc[i][0] = fmaf(xv.x, w0.x, acc[i][0]); acc[i][0] = fmaf(xv.y, w1.x, acc[i][0]);
                acc[i][0] = fmaf(xv.z, w2.x, acc[i][0]); acc[i][0] = fmaf(xv.w, w3.x, acc[i][0]);
                acc[i][1] = fmaf(xv.x, w0.y, acc[i][1]); acc[i][1] = fmaf(xv.y, w1.y, acc[i][1]);
                acc[i][1] = fmaf(xv.z, w2.y, acc[i][1]); acc[i][1] = fmaf(xv.w, w3.y, acc[i][1]);
                acc[i][2] = fmaf(xv.x, w0.z, acc[i][2]); acc[i][2] = fmaf(xv.y, w1.z, acc[i][2]);
                acc[i][2] = fmaf(xv.z, w2.z, acc[i][2]); acc[i][2] = fmaf(xv.w, w3.z, acc[i][2]);
                acc[i][3] = fmaf(xv.x, w0.w, acc[i][3]); acc[i][3] = fmaf(xv.y, w1.w, acc[i][3]);
                acc[i][3] = fmaf(xv.z, w2.w, acc[i][3]); acc[i][3] = fmaf(xv.w, w3.w, acc[i][3]);
            }
        }
        float4 bb = *(const float4*)(b1 + c0);
        #pragma unroll
        for (int i = 0; i < 4; i++) {
            float o0 = acc[i][0] + bb.x, o1 = acc[i][1] + bb.y;
            float o2 = acc[i][2] + bb.z, o3 = acc[i][3] + bb.w;
            o0 = o0 > 0.f ? o0 : __expf(o0) - 1.f;
            o1 = o1 > 0.f ? o1 : __expf(o1) - 1.f;
            o2 = o2 > 0.f ? o2 : __expf(o2) - 1.f;
            o3 = o3 > 0.f ? o3 : __expf(o3) - 1.f;
            float4 ov = {o0, o1, o2, o3};
            *(float4*)(act + (g * 4 + i) * ACT_STRIDE + c0) = ov;
        }
    }
    __syncthreads();

    {   // ---- Phase C: h2 = act @ W2, k-split across waves ----
        const int q  = t & 15;                 // c-quad: cols q*4..q*4+3 of 64
        const int ng = (t >> 4) & 3;           // node group
        const int kb = wv * 64;                // this wave's k-chunk
        float a[4][4];
        #pragma unroll
        for (int i = 0; i < 4; i++)
            #pragma unroll
            for (int m = 0; m < 4; m++) a[i][m] = 0.f;
        for (int kk = 0; kk < 64; kk += 4) {
            const int k = kb + kk;
            float4 w0 = *(const float4*)(W2 + (size_t)(k + 0) * OUT_DIM + q * 4);
            float4 w1 = *(const float4*)(W2 + (size_t)(k + 1) * OUT_DIM + q * 4);
            float4 w2 = *(const float4*)(W2 + (size_t)(k + 2) * OUT_DIM + q * 4);
            float4 w3 = *(const float4*)(W2 + (size_t)(k + 3) * OUT_DIM + q * 4);
            #pragma unroll
            for (int i = 0; i < 4; i++) {
                float4 xv = *(const float4*)(act + (ng * 4 + i) * ACT_STRIDE + k);
                a[i][0] = fmaf(xv.x, w0.x, a[i][0]); a[i][0] = fmaf(xv.y, w1.x, a[i][0]);
                a[i][0] = fmaf(xv.z, w2.x, a[i][0]); a[i][0] = fmaf(xv.w, w3.x, a[i][0]);
                a[i][1] = fmaf(xv.x, w0.y, a[i][1]); a[i][1] = fmaf(xv.y, w1.y, a[i][1]);
                a[i][1] = fmaf(xv.z, w2.y, a[i][1]); a[i][1] = fmaf(xv.w, w3.y, a[i][1]);
                a[i][2] = fmaf(xv.x, w0.z, a[i][2]); a[i][2] = fmaf(xv.y, w1.z, a[i][2]);
                a[i][2] = fmaf(xv.z, w2.z, a[i][2]); a[i][2] = fmaf(xv.w, w3.z, a[i][2]);
                a[i][3] = fmaf(xv.x, w0.w, a[i][3]); a[i][3] = fmaf(xv.y, w1.w, a[i][3]);
                a[i][3] = fmaf(xv.z, w2.w, a[i][3]); a[i][3] = fmaf(xv.w, w3.w, a[i][3]);
            }
        }
        float* pc = xs;                        // alias: xs no longer needed
        #pragma unroll
        for (int i = 0; i < 4; i++) {
            float4 pv = {a[i][0], a[i][1], a[i][2], a[i][3]};
            *(float4*)(pc + wv * PC_WCHUNK + (ng * 4 + i) * PC_STRIDE + q * 4) = pv;
        }
    }
    __syncthreads();

    {   // ---- Reduce partials + epilogue ----
        const float* pc = xs;
        const int n  = t >> 4;                 // node 0..15
        const int c0 = (t & 15) * 4;           // cols 0..63
        float4 r = {0, 0, 0, 0};
        #pragma unroll
        for (int w = 0; w < 4; w++) {
            float4 p = *(const float4*)(pc + w * PC_WCHUNK + n * PC_STRIDE + c0);
            r.x += p.x; r.y += p.y; r.z += p.z; r.w += p.w;
        }
        const int node = nodeBase + n;
        *(float4*)(h2 + (size_t)node * OUT_DIM + c0) = r;
        float4 aw = *(const float4*)(a_src2 + c0);
        float4 dw = *(const float4*)(a_dst2 + c0);
        float s = r.x * aw.x + r.y * aw.y + r.z * aw.z + r.w * aw.w;
        float d = r.x * dw.x + r.y * dw.y + r.z * dw.z + r.w * dw.w;
        #pragma unroll
        for (int off = 8; off; off >>= 1) {
            s += __shfl_down(s, off, 16);
            d += __shfl_down(d, off, 16);
        }
        if ((t & 15) == 0) { as2[node] = s; ad2[node] = d; }
    }
}

// ---------------------------------------------------------------------------
// Layer-2 aggregation + bias + fc dot, fused, unroll x4. One wave per node.
// ---------------------------------------------------------------------------
__global__ __launch_bounds__(256) void agg2_final_kernel(
    const int* __restrict__ rowptr, const int* __restrict__ srcS,
    const float* __restrict__ h2, const float* __restrict__ as2,
    const float* __restrict__ ad2, const float* __restrict__ b2,
    const float* __restrict__ fc_w, const float* __restrict__ fc_b,
    float* __restrict__ out)
{
    int gid  = blockIdx.x * blockDim.x + threadIdx.x;
    int n    = gid >> 6;
    int lane = threadIdx.x & 63;
    if (n >= N_NODES) return;
    const float adh = ad2[n];
    const int e0 = rowptr[n], e1 = rowptr[n + 1];

    float acc = 0.f, den = 0.f;
    int e = e0;
    for (; e + 4 <= e1; e += 4) {
        int s0 = srcS[e], s1 = srcS[e + 1], s2 = srcS[e + 2], s3 = srcS[e + 3];
        float a0 = as2[s0] + adh;
        float a1 = as2[s1] + adh;
        float a2 = as2[s2] + adh;
        float a3 = as2[s3] + adh;
        float v0 = h2[(size_t)s0 * OUT_DIM + lane];
        float v1 = h2[(size_t)s1 * OUT_DIM + lane];
        float v2 = h2[(size_t)s2 * OUT_DIM + lane];
        float v3 = h2[(size_t)s3 * OUT_DIM + lane];
        a0 = a0 > 0.f ? a0 : NEG_SLOPE * a0;
        a1 = a1 > 0.f ? a1 : NEG_SLOPE * a1;
        a2 = a2 > 0.f ? a2 : NEG_SLOPE * a2;
        a3 = a3 > 0.f ? a3 : NEG_SLOPE * a3;
        float w0 = __expf(a0), w1 = __expf(a1), w2 = __expf(a2), w3 = __expf(a3);
        acc = fmaf(w0, v0, acc); acc = fmaf(w1, v1, acc);
        acc = fmaf(w2, v2, acc); acc = fmaf(w3, v3, acc);
        den += (w0 + w1) + (w2 + w3);
    }
    for (; e < e1; e++) {
        int s = srcS[e];
        float a = as2[s] + adh;
        a = a > 0.f ? a : NEG_SLOPE * a;
        float w = __expf(a);
        acc = fmaf(w, h2[(size_t)s * OUT_DIM + lane], acc);
        den += w;
    }
    float v = acc / (den + 1e-16f) + b2[lane];
    float r = v * fc_w[lane];
    #pragma unroll
    for (int off = 32; off; off >>= 1) r += __shfl_down(r, off, 64);
    if (lane == 0) out[n] = r + fc_b[0];
}

extern "C" void kernel_launch(void* const* d_in, const int* in_sizes, int n_in,
                              void* d_out, int out_size, void* d_ws, size_t ws_size,
                              hipStream_t stream)
{
    const float* x      = (const float*)d_in[0];
    const int*   ei     = (const int*)d_in[1];
    const float* W1     = (const float*)d_in[2];
    const float* a_src1 = (const float*)d_in[3];
    const float* a_dst1 = (const float*)d_in[4];
    const float* b1     = (const float*)d_in[5];
    const float* W2     = (const float*)d_in[6];
    const float* a_src2 = (const float*)d_in[7];
    const float* a_dst2 = (const float*)d_in[8];
    const float* b2     = (const float*)d_in[9];
    const float* fc_w   = (const float*)d_in[10];
    const float* fc_b   = (const float*)d_in[11];
    float* out = (float*)d_out;

    const int* srcA = ei;
    const int* dstA = ei + N_EDGES;

    // workspace layout (xagg eliminated)
    float* ws = (float*)d_ws;
    size_t off = 0;
    float* h2      = ws + off; off += (size_t)N_NODES * OUT_DIM;  // 12.8 MB
    float* as1     = ws + off; off += (size_t)N_NODES * HEADS;
    float* ad1     = ws + off; off += (size_t)N_NODES * HEADS;
    float* as2     = ws + off; off += N_NODES;
    float* ad2     = ws + off; off += N_NODES;
    float* p_src   = ws + off; off += IN_DIM * HEADS;
    float* p_dst   = ws + off; off += IN_DIM * HEADS;
    int* rowptr    = (int*)(ws + off); off += N_NODES + 2;
    int* srcSorted = (int*)(ws + off); off += E_TOT;
    int* zstart    = (int*)(ws + off);
    int* deg       = (int*)(ws + off); off += N_NODES;
    int* cursor    = (int*)(ws + off); off += N_NODES;
    hipMemsetAsync(zstart, 0, 2 * N_NODES * sizeof(int), stream);

    // CSR build
    count_kernel<<<(E_TOT + 255) / 256, 256, 0, stream>>>(dstA, deg);
    scan_kernel<<<1, 1024, 0, stream>>>(deg, rowptr);
    fill_kernel<<<(E_TOT + 255) / 256, 256, 0, stream>>>(srcA, dstA, rowptr, cursor, srcSorted);

    // layer-1 logit projections (h1 never materialized)
    prep_kernel<<<1, 512, 0, stream>>>(W1, a_src1, a_dst1, p_src, p_dst);
    proj1_kernel<<<N_NODES / 4, 256, 0, stream>>>(x, p_src, p_dst, as1, ad1);

    // fused layer-1 aggregation + MLP (gather -> LDS -> W1 -> ELU -> W2)
    gat1_mlp_kernel<<<N_NODES / 16, 256, 0, stream>>>(rowptr, srcSorted, x, as1, ad1,
                                                      W1, b1, W2, a_src2, a_dst2,
                                                      h2, as2, ad2);

    // layer 2 + final
    agg2_final_kernel<<<(N_NODES * 64 + 255) / 256, 256, 0, stream>>>(rowptr, srcSorted, h2, as2, ad2, b2, fc_w, fc_b, out);
}